// Round 13
// baseline (9476.508 us; speedup 1.0000x reference)
//
#include <hip/hip_runtime.h>
#include <math.h>

typedef __bf16 bf16x8 __attribute__((ext_vector_type(8)));
typedef float f32x4 __attribute__((ext_vector_type(4)));

namespace {

constexpr int kB = 16;
constexpr int kT = 1024;
constexpr int kD = 1024;
constexpr int kN = 8;
constexpr float kScale = 0.03125f;  // 1/sqrt(1024)

constexpr unsigned long long kSent = ~0ull;      // 8B poison
constexpr unsigned kSentW = 0xFFFFFFFFu;         // 4B poison word (NaN)
constexpr int kHS = 3 * kB * kD;                 // shorts per h-split parity buf
constexpr int kRW = 2 * kB * kD;                 // floats per rw parity buf

__device__ inline unsigned short f2bf(float f) {  // RNE f32->bf16 bits
  unsigned u = __float_as_uint(f);
  u += 0x7FFFu + ((u >> 16) & 1u);
  return (unsigned short)(u >> 16);
}
__device__ inline float bf2f(unsigned short b) {
  return __uint_as_float(((unsigned)b) << 16);
}

__device__ inline float fast_tanh(float x) {       // (1-t)/(1+t), t=e^{-2|x|}
  const float ax = fabsf(x);
  const float t = __expf(-2.f * ax);
  const float r = (1.f - t) / (1.f + t);
  return copysignf(r, x);
}

// Fence-free cross-block transfer: relaxed agent-scope atomics compile to
// sc0|sc1 (L1+L2-bypass) accesses served by the device-coherent point.
__device__ inline void atst8(void* p, unsigned long long v) {
  __hip_atomic_store((unsigned long long*)p, v, __ATOMIC_RELAXED,
                     __HIP_MEMORY_SCOPE_AGENT);
}
__device__ inline unsigned long long atld8(const void* p) {
  return __hip_atomic_load((unsigned long long*)p, __ATOMIC_RELAXED,
                           __HIP_MEMORY_SCOPE_AGENT);
}
__device__ inline void atstf(float* p, float v) {
  __hip_atomic_store(p, v, __ATOMIC_RELAXED, __HIP_MEMORY_SCOPE_AGENT);
}
__device__ inline void atstu(unsigned* p, unsigned v) {
  __hip_atomic_store(p, v, __ATOMIC_RELAXED, __HIP_MEMORY_SCOPE_AGENT);
}
__device__ inline unsigned atldu(const unsigned* p) {
  return __hip_atomic_load((unsigned*)p, __ATOMIC_RELAXED,
                           __HIP_MEMORY_SCOPE_AGENT);
}

union U16 { unsigned long long ll[2]; unsigned wrd[4]; bf16x8 bv; float4 f4; };

// ---------------------------------------------------------------------------
// h-split store, consumer-lane-major layout (round-3/4 proven):
// element (part, w, j, half, l) at short-offset
//   part*16384 + ((w*8+j)<<9) + (half<<8) + l*4,  l = q*16 + batch.
__device__ inline void store_split(unsigned short* hs, int b, int d4, float4 h) {
  union { unsigned short u[4]; unsigned long long ll; } c2, c1, c0;
  float hv[4] = {h.x, h.y, h.z, h.w};
#pragma unroll
  for (int e = 0; e < 4; ++e) {
    unsigned short x = f2bf(hv[e]);
    float r = hv[e] - bf2f(x);
    unsigned short y = f2bf(r);
    float r2 = r - bf2f(y);
    unsigned short z = f2bf(r2);
    c2.u[e] = x; c1.u[e] = y; c0.u[e] = z;
  }
  const int w = d4 >> 8;
  const int j = (d4 >> 5) & 7;
  const int q = (d4 >> 3) & 3;
  const int hf = (d4 >> 2) & 1;
  const int off = ((w * 8 + j) << 9) + (hf << 8) + ((q * 16 + b) << 2);
  atst8(&hs[0 * 16384 + off], c2.ll);
  atst8(&hs[1 * 16384 + off], c1.ll);
  atst8(&hs[2 * 16384 + off], c0.ll);
}

// ---------------------------------------------------------------------------
// Round-13 = round-12 fused kernel with PIPELINED POLLS: the tag spin and
// the rw poll keep one sample permanently in flight (issue sample i+1
// before waiting on sample i). Serial polling had detect lag ~1.5-2 RT
// (sample spacing = RT + check + sleep); pipelined sampling spaces samples
// at ~check+sleep (<50ns), so detect lag drops to ~1 RT per hop. Poll
// addresses and widths are unchanged (proven-narrow class: tag lines have
// 64 pollers + 1 post-drain writer; rw is a 4-word chunk) -- this is not
// the round-9/10 wide-pass/data-ping-pong pattern. Dangling in-flight
// samples at loop exit are side-effect-free and drained by the later
// publish vmcnt(0). Numerics BIT-IDENTICAL to round 12.
//
// Everything else round-12 verbatim: blocks 0..63 scan, blocks 64.. xproj
// producers (time-major, atomic C-writes, data-as-flag xp with late
// validation); scan protocol = data-as-flag hsplit + rw, advisory
// line-private tags (drain -> splits -> tag), certified repoison, merged
// attention (one barrier/iter), tape in registers, fast transcendentals.
__global__ __launch_bounds__(256, 1)
void scan_kernel(const float* __restrict__ X, const float* __restrict__ Wx,
                 const float* __restrict__ Wh, const float* __restrict__ Ww,
                 const float* __restrict__ bh,
                 float* __restrict__ hall,              // [B,T,D] xp -> h
                 unsigned short* __restrict__ hsplit,   // [2][3][4][8][512] bf16
                 float* __restrict__ rw,                // [2][2][16][1024] f32
                 unsigned* __restrict__ hmark,          // [4][16] tags, 64B apart
                 float* __restrict__ out_tape,          // [B,N,D]
                 float* __restrict__ out_h) {           // [B,D]
  __shared__ float Xs[16][132];         // xproj staging (producer blocks)
  __shared__ float Ws[16][132];
  __shared__ f32x4 Cred[2][4][2][64];   // scan: cross-wave C partials (dbuf)
  __shared__ float red2[4][20];         // scan: [w][0..7]=wv [8..15]=h [16]=h.wv

  const int bid = blockIdx.x;
  const int tid = threadIdx.x;

  if (bid >= 64) {
    // ---- xproj producer: C[m,n] = sum_k X[m,k]*Wx[n,k] (round-1 proven
    //      body; time-major tile order; atomic C-writes for IC visibility)
    const int e = bid - 64;
    const int t_blk = e >> 7;           // 0..7  (time stratum, early first)
    const int b = (e >> 3) & 15;        // batch
    const int nb = e & 7;               // column block
    const int m0 = b * kT + t_blk * 128;
    const int n0 = nb * 128;
    const int tx = tid & 15;
    const int ty = tid >> 4;
    const int lr = tid >> 2;
    const int lc = (tid & 3) * 4;

    float acc[8][8];
#pragma unroll
    for (int i = 0; i < 8; ++i)
#pragma unroll
      for (int j = 0; j < 8; ++j) acc[i][j] = 0.f;

    for (int k0 = 0; k0 < kD; k0 += 16) {
      const float4 xa = *(const float4*)&X[(size_t)(m0 + lr) * kD + k0 + lc];
      const float4 xb = *(const float4*)&X[(size_t)(m0 + lr + 64) * kD + k0 + lc];
      const float4 wa = *(const float4*)&Wx[(size_t)(n0 + lr) * kD + k0 + lc];
      const float4 wb = *(const float4*)&Wx[(size_t)(n0 + lr + 64) * kD + k0 + lc];
      __syncthreads();
      Xs[lc + 0][lr] = xa.x; Xs[lc + 1][lr] = xa.y; Xs[lc + 2][lr] = xa.z; Xs[lc + 3][lr] = xa.w;
      Xs[lc + 0][lr + 64] = xb.x; Xs[lc + 1][lr + 64] = xb.y; Xs[lc + 2][lr + 64] = xb.z; Xs[lc + 3][lr + 64] = xb.w;
      Ws[lc + 0][lr] = wa.x; Ws[lc + 1][lr] = wa.y; Ws[lc + 2][lr] = wa.z; Ws[lc + 3][lr] = wa.w;
      Ws[lc + 0][lr + 64] = wb.x; Ws[lc + 1][lr + 64] = wb.y; Ws[lc + 2][lr + 64] = wb.z; Ws[lc + 3][lr + 64] = wb.w;
      __syncthreads();
#pragma unroll
      for (int k = 0; k < 16; ++k) {
        float a[8], bb[8];
        *(float4*)&a[0] = *(const float4*)&Xs[k][ty * 8];
        *(float4*)&a[4] = *(const float4*)&Xs[k][ty * 8 + 4];
        *(float4*)&bb[0] = *(const float4*)&Ws[k][tx * 8];
        *(float4*)&bb[4] = *(const float4*)&Ws[k][tx * 8 + 4];
#pragma unroll
        for (int i = 0; i < 8; ++i)
#pragma unroll
          for (int j = 0; j < 8; ++j) acc[i][j] += a[i] * bb[j];
      }
    }
#pragma unroll
    for (int i = 0; i < 8; ++i) {
      union { float f[8]; unsigned long long ll[4]; } row;
#pragma unroll
      for (int j = 0; j < 8; ++j) row.f[j] = acc[i][j];
      float* p = &hall[(size_t)(m0 + ty * 8 + i) * kD + n0 + tx * 8];
      atst8(p + 0, row.ll[0]);
      atst8(p + 2, row.ll[1]);
      atst8(p + 4, row.ll[2]);
      atst8(p + 6, row.ll[3]);
    }
    return;
  }

  // ===================== scan (round-12 body + pipelined polls) ============
  const int g = bid;
  const int w = tid >> 6;    // wave 0..3 (split-K: k range [256w, 256w+256))
  const int ln = tid & 63;
  const int bat = ln & 15;   // A-row (batch) / B-col selector
  const bool tapeb = (g < kB);
  const int col0 = (g & 31) * 32;
  const int matw = g >> 5;

  // ---- weight prologue (plain loads; weights immutable) ----
  bf16x8 wf[3][2][8];
  {
    const float* Wsrc = matw ? Ww : Wh;
#pragma unroll
    for (int ct = 0; ct < 2; ++ct)
#pragma unroll
      for (int j = 0; j < 8; ++j) {
        const float* src = &Wsrc[(size_t)(col0 + ct * 16 + bat) * kD + (w * 8 + j) * 32 + ((ln >> 4)) * 8];
        float v[8];
        *(float4*)&v[0] = *(const float4*)src;
        *(float4*)&v[4] = *(const float4*)(src + 4);
        union { unsigned short u[8]; bf16x8 b; } e2, e1, e0;
#pragma unroll
        for (int e = 0; e < 8; ++e) {
          unsigned short a = f2bf(v[e]);
          float r = v[e] - bf2f(a);
          unsigned short b2 = f2bf(r);
          float r2 = r - bf2f(b2);
          unsigned short c = f2bf(r2);
          e2.u[e] = a; e1.u[e] = b2; e0.u[e] = c;
        }
        wf[0][ct][j] = e2.b;
        wf[1][ct][j] = e1.b;
        wf[2][ct][j] = e0.b;
      }
  }

  // ---- tape-block bootstrap: tape=0 (registers), h(1)=tanh(xp0) ----
  float4 hprev = make_float4(0.f, 0.f, 0.f, 0.f);
  float4 bh4 = make_float4(0.f, 0.f, 0.f, 0.f);
  float4 tpr[kN];                       // the tape slice: thread-private
#pragma unroll
  for (int n = 0; n < kN; ++n) tpr[n] = make_float4(0.f, 0.f, 0.f, 0.f);
  const int d4 = tid * 4;
  if (tapeb) {
    float* px0 = &hall[(size_t)g * kT * kD + d4];
    U16 ux;
    for (;;) {                         // poll xp0 (xproj data-as-flag)
      ux.ll[0] = atld8(px0); ux.ll[1] = atld8(px0 + 2);
      int bad = 0;
#pragma unroll
      for (int k2 = 0; k2 < 4; ++k2) bad |= (ux.wrd[k2] == kSentW);
      if (!bad) break;
      __builtin_amdgcn_s_sleep(1);
    }
    asm volatile("" ::: "memory");
    hprev.x = tanhf(ux.f4.x); hprev.y = tanhf(ux.f4.y);
    hprev.z = tanhf(ux.f4.z); hprev.w = tanhf(ux.f4.w);
    *(float4*)px0 = hprev;             // plain: host-read-only afterward
    store_split(hsplit, g, d4, hprev);           // parity 0 = h(1)
    asm volatile("s_waitcnt vmcnt(0)" ::: "memory");  // one-time drain
    if (ln == 0) atstu(&hmark[(w * 16 + g) * 16], 1u);  // advisory tag
    bh4 = *(const float4*)&bh[d4];
  }

  for (int t = 0; t < kT; ++t) {
    const int p = t & 1;
    const unsigned short* hb = hsplit + p * kHS;

    // speculative xp load (validated LATE, before the tanh): latency hides
    // under the whole step; producer is far ahead after the first steps
    U16 uxp;
    float* px = nullptr;
    if (tapeb && t < kT - 1) {
      px = &hall[((size_t)g * kT + (t + 1)) * kD + d4];
      uxp.ll[0] = atld8(px); uxp.ll[1] = atld8(px + 2);
    }

    // ---- phase 1: advisory tag spin, PIPELINED (next sample in flight
    //      while the previous one is checked; detect lag ~1 RT) ----
    {
      const unsigned need = (unsigned)(t + 1);
      const unsigned* mk = &hmark[(w * 16 + bat) * 16];
      unsigned vin = 0;
      if ((ln >> 4) == 0) vin = atldu(mk);
      for (;;) {
        const unsigned vcur = vin;
        if ((ln >> 4) == 0) vin = atldu(mk);   // sample i+1 in flight
        const unsigned bc = __shfl(vcur, bat); // waits on sample i only
        if (bc >= need) break;
        __builtin_amdgcn_s_sleep(1);
      }
      asm volatile("" ::: "memory");
    }
    // A fragments: one-shot dense lane-major pass, sentinel-validated (an
    // 8B chunk of 0xFFFF shorts is unreachable by finite bf16 split parts).
    U16 uf[3][8];
    const unsigned short* hw0 = hb + (w << 12) + (ln << 2);  // w*4096 + ln*4
    for (;;) {
      int bad = 0;
#pragma unroll
      for (int j = 0; j < 8; ++j) {
        const unsigned short* p0 = hw0 + (j << 9);
#pragma unroll
        for (int part = 0; part < 3; ++part) {
          uf[part][j].ll[0] = atld8(p0 + part * 16384);
          uf[part][j].ll[1] = atld8(p0 + part * 16384 + 256);
        }
      }
#pragma unroll
      for (int j = 0; j < 8; ++j)
#pragma unroll
        for (int part = 0; part < 3; ++part)
          bad |= (uf[part][j].ll[0] == kSent) | (uf[part][j].ll[1] == kSent);
      if (!bad) break;
      __builtin_amdgcn_s_sleep(1);
    }
    asm volatile("" ::: "memory");

    // ---- 6-product triple-split MFMA ----
    f32x4 zf = {0.f, 0.f, 0.f, 0.f};
    f32x4 acc[2][2] = {{zf, zf}, {zf, zf}};
#pragma unroll
    for (int j = 0; j < 8; ++j) {
      const int s = j & 1;
#pragma unroll
      for (int ct = 0; ct < 2; ++ct) {
        f32x4 a = acc[ct][s];
        a = __builtin_amdgcn_mfma_f32_16x16x32_bf16(uf[0][j].bv, wf[0][ct][j], a, 0, 0, 0);
        a = __builtin_amdgcn_mfma_f32_16x16x32_bf16(uf[0][j].bv, wf[1][ct][j], a, 0, 0, 0);
        a = __builtin_amdgcn_mfma_f32_16x16x32_bf16(uf[1][j].bv, wf[0][ct][j], a, 0, 0, 0);
        a = __builtin_amdgcn_mfma_f32_16x16x32_bf16(uf[0][j].bv, wf[2][ct][j], a, 0, 0, 0);
        a = __builtin_amdgcn_mfma_f32_16x16x32_bf16(uf[2][j].bv, wf[0][ct][j], a, 0, 0, 0);
        a = __builtin_amdgcn_mfma_f32_16x16x32_bf16(uf[1][j].bv, wf[1][ct][j], a, 0, 0, 0);
        acc[ct][s] = a;
      }
    }
    Cred[p][w][0][ln] = acc[0][0] + acc[0][1];
    Cred[p][w][1][ln] = acc[1][0] + acc[1][1];
    __syncthreads();
    if (tid < 128) {
      const int ct = tid >> 6, l2 = tid & 63;
      f32x4 sv = Cred[p][0][ct][l2] + Cred[p][1][ct][l2] +
                 Cred[p][2][ct][l2] + Cred[p][3][ct][l2];
      float* dst = rw + p * kRW + matw * (kB * kD);
      const int col = col0 + ct * 16 + (l2 & 15);
      const int m0 = (l2 >> 4) * 4;  // C/D: col=lane&15, row=(lane>>4)*4+reg (m89)
#pragma unroll
      for (int r = 0; r < 4; ++r) atstf(&dst[(size_t)(m0 + r) * kD + col], sv[r]);
      // no drain, no flag: consumers validate the data itself
    }
    // no second barrier: next iteration writes Cred[p^1]

    if (!tapeb) continue;

    // ---- P2 (tape blocks), merged-attention flow (tape in registers) ----
    const int b = g;
    float* rwp = rw + p * kRW;
    float* pr = &rwp[b * kD + d4];
    float* pw = &rwp[kB * kD + b * kD + d4];

    // first rw sample in flight before the h-dot tree (poll pipelining)
    U16 ur, uw;
    ur.ll[0] = atld8(pr); ur.ll[1] = atld8(pr + 2);
    uw.ll[0] = atld8(pw); uw.ll[1] = atld8(pw + 2);

    // (1) h-dot tree on the OLD tape -- useful work while rw propagates
    {
      float ph[kN];
#pragma unroll
      for (int n = 0; n < kN; ++n)
        ph[n] = hprev.x * tpr[n].x + hprev.y * tpr[n].y +
                hprev.z * tpr[n].z + hprev.w * tpr[n].w;
#pragma unroll
      for (int off = 32; off > 0; off >>= 1)
#pragma unroll
        for (int n = 0; n < kN; ++n) ph[n] += __shfl_xor(ph[n], off);
      if (ln == 0)
#pragma unroll
        for (int n = 0; n < kN; ++n) red2[w][8 + n] = ph[n];
    }

    // (2) PIPELINED poll of wv AND rh (next sample in flight while the
    //     previous is checked; both must be valid pre-barrier for the
    //     repoison certification)
    float4 rh4, wv4;
    for (;;) {
      U16 urn, uwn;
      urn.ll[0] = atld8(pr); urn.ll[1] = atld8(pr + 2);
      uwn.ll[0] = atld8(pw); uwn.ll[1] = atld8(pw + 2);
      int bad = 0;
#pragma unroll
      for (int k2 = 0; k2 < 4; ++k2)
        bad |= (ur.wrd[k2] == kSentW) | (uw.wrd[k2] == kSentW);
      if (!bad) { rh4 = ur.f4; wv4 = uw.f4; break; }
      ur = urn; uw = uwn;
      __builtin_amdgcn_s_sleep(1);
    }
    asm volatile("" ::: "memory");       // no reorder across the data-poll
    // (3) re-poison this rw parity for its t+2 reuse (drained by the
    //     barrier's implicit vmcnt(0) below)
    atst8(pr, kSent); atst8(pr + 2, kSent);
    atst8(pw, kSent); atst8(pw + 2, kSent);

    // (4) wv-dot tree: wv.tp_old[n] (8) + h.wv (1)
    {
      float pv[9];
#pragma unroll
      for (int n = 0; n < kN; ++n)
        pv[n] = wv4.x * tpr[n].x + wv4.y * tpr[n].y +
                wv4.z * tpr[n].z + wv4.w * tpr[n].w;
      pv[8] = hprev.x * wv4.x + hprev.y * wv4.y + hprev.z * wv4.z + hprev.w * wv4.w;
#pragma unroll
      for (int off = 32; off > 0; off >>= 1)
#pragma unroll
        for (int n = 0; n < 9; ++n) pv[n] += __shfl_xor(pv[n], off);
      if (ln == 0) {
#pragma unroll
        for (int n = 0; n < kN; ++n) red2[w][n] = pv[n];
        red2[w][16] = pv[8];
      }
    }
    __syncthreads();   // the ONLY attn barrier (pools rw validation + red2)

    // (5) repoison hsplit parity p (own 3 chunks; certified consumed by the
    //     barrier; drained by the publish vmcnt(0) below)
    {
      unsigned short* hp0 = hsplit + p * kHS;
      const int off = (((d4 >> 8) * 8 + ((d4 >> 5) & 7)) << 9) +
                      (((d4 >> 2) & 1) << 8) + ((((d4 >> 3) & 3) * 16 + b) << 2);
      atst8(&hp0[0 * 16384 + off], kSent);
      atst8(&hp0[1 * 16384 + off], kSent);
      atst8(&hp0[2 * 16384 + off], kSent);
    }

    // (6) cross-wave sums + write-attention softmax
    float s_h[kN], s_hwv;
    float wa[kN];
    {
      float mx = -1e30f;
#pragma unroll
      for (int n = 0; n < kN; ++n) {
        const float sc = kScale * (red2[0][n] + red2[1][n] + red2[2][n] + red2[3][n]);
        wa[n] = sc;
        mx = fmaxf(mx, sc);
        s_h[n] = red2[0][8 + n] + red2[1][8 + n] + red2[2][8 + n] + red2[3][8 + n];
      }
      s_hwv = red2[0][16] + red2[1][16] + red2[2][16] + red2[3][16];
      float ssum = 0.f;
#pragma unroll
      for (int n = 0; n < kN; ++n) { wa[n] = __expf(wa[n] - mx); ssum += wa[n]; }
      const float inv = 1.f / ssum;
#pragma unroll
      for (int n = 0; n < kN; ++n) wa[n] *= inv;
    }

    // (7) tape update, in registers (thread-private slice)
#pragma unroll
    for (int n = 0; n < kN; ++n) {
      const float wn = wa[n], om = 1.f - wn;
      tpr[n].x = tpr[n].x * om + wv4.x * wn;
      tpr[n].y = tpr[n].y * om + wv4.y * wn;
      tpr[n].z = tpr[n].z * om + wv4.z * wn;
      tpr[n].w = tpr[n].w * om + wv4.w * wn;
    }

    if (t == kT - 1) {
#pragma unroll
      for (int n = 0; n < kN; ++n)
        *(float4*)&out_tape[((size_t)b * kN + n) * kD + d4] = tpr[n];
      *(float4*)&out_h[b * kD + d4] = hprev;
      continue;
    }

    // (8) read-attention via the distributive identity:
    //     h.tp_new[n] = (1-wa[n])*s_h[n] + wa[n]*s_hwv
    float ra[kN];
    {
      float mx = -1e30f;
#pragma unroll
      for (int n = 0; n < kN; ++n) {
        const float sc = kScale * (s_h[n] * (1.f - wa[n]) + s_hwv * wa[n]);
        ra[n] = sc;
        mx = fmaxf(mx, sc);
      }
      float ssum = 0.f;
#pragma unroll
      for (int n = 0; n < kN; ++n) { ra[n] = __expf(ra[n] - mx); ssum += ra[n]; }
      const float inv = 1.f / ssum;
#pragma unroll
      for (int n = 0; n < kN; ++n) ra[n] *= inv;
    }

    // (9) rv from the UPDATED register tape
    float4 rv = make_float4(0.f, 0.f, 0.f, 0.f);
#pragma unroll
    for (int n = 0; n < kN; ++n) {
      rv.x += ra[n] * tpr[n].x; rv.y += ra[n] * tpr[n].y;
      rv.z += ra[n] * tpr[n].z; rv.w += ra[n] * tpr[n].w;
    }

    // (9b) LATE xp validation (speculative load issued at step top; xproj
    //      writes each location once, atomically per 8B chunk)
    for (;;) {
      int bad = 0;
#pragma unroll
      for (int k2 = 0; k2 < 4; ++k2) bad |= (uxp.wrd[k2] == kSentW);
      if (!bad) break;
      __builtin_amdgcn_s_sleep(1);
      uxp.ll[0] = atld8(px); uxp.ll[1] = atld8(px + 2);
    }
    asm volatile("" ::: "memory");
    const float4 xp4 = uxp.f4;

    float4 hn;
    hn.x = fast_tanh(xp4.x + rh4.x + rv.x + bh4.x);
    hn.y = fast_tanh(xp4.y + rh4.y + rv.y + bh4.y);
    hn.z = fast_tanh(xp4.z + rh4.z + rv.z + bh4.z);
    hn.w = fast_tanh(xp4.w + rh4.w + rv.w + bh4.w);

    // (10) publish, round-8 proven order: (near-free) drain enforcing
    //      repoison->splits visibility order, splits, THEN tag, hall last.
    asm volatile("s_waitcnt vmcnt(0)" ::: "memory");
    store_split(hsplit + (p ^ 1) * kHS, b, d4, hn);   // publish h(t+2)
    if (ln == 0) atstu(&hmark[(w * 16 + b) * 16], (unsigned)(t + 2));  // advisory
    *(float4*)&hall[((size_t)b * kT + (t + 1)) * kD + d4] = hn;  // off-path
    hprev = hn;
  }
}

}  // namespace

extern "C" void kernel_launch(void* const* d_in, const int* in_sizes, int n_in,
                              void* d_out, int out_size, void* d_ws, size_t ws_size,
                              hipStream_t stream) {
  const float* x  = (const float*)d_in[0];
  const float* Wh = (const float*)d_in[1];
  const float* Wx = (const float*)d_in[2];
  const float* bh = (const float*)d_in[3];
  const float* Ww = (const float*)d_in[4];

  float* out = (float*)d_out;
  float* hall = out;                                  // [B,T,D]
  float* out_tape = out + (size_t)kB * kT * kD;       // [B,N,D]
  float* out_h = out_tape + (size_t)kB * kN * kD;     // [B,D]

  // ws: [0,4096) hmark tags (64 x 64B lines); [4096,+192K) hsplit[2];
  //     then rw[2] (256K). hsplit, rw AND hall are NaN-poisoned each launch
  //     (stream-ordered before the fused kernel: data-as-flag bootstrap).
  unsigned* hmark = (unsigned*)d_ws;
  unsigned short* hsplit = (unsigned short*)((char*)d_ws + 4096);
  float* rw = (float*)((char*)d_ws + 4096 + 2 * kHS * (int)sizeof(unsigned short));

  hipMemsetAsync(d_ws, 0, 4096, stream);             // tags = 0
  hipMemsetAsync((char*)d_ws + 4096, 0xFF,
                 2 * kHS * sizeof(unsigned short) + 2 * kRW * sizeof(float),
                 stream);                            // poison hsplit + rw
  hipMemsetAsync(hall, 0xFF, (size_t)kB * kT * kD * sizeof(float),
                 stream);                            // poison hall (xp flags)

  scan_kernel<<<64 + 1024, 256, 0, stream>>>(x, Wx, Wh, Ww, bh, hall, hsplit,
                                             rw, hmark, out_tape, out_h);
}

// Round 14
// 9186.722 us; speedup vs baseline: 1.0315x; 1.0315x over previous
//
#include <hip/hip_runtime.h>
#include <math.h>

typedef __bf16 bf16x8 __attribute__((ext_vector_type(8)));
typedef float f32x4 __attribute__((ext_vector_type(4)));

namespace {

constexpr int kB = 16;
constexpr int kT = 1024;
constexpr int kD = 1024;
constexpr int kN = 8;
constexpr float kScale = 0.03125f;  // 1/sqrt(1024)

constexpr unsigned long long kSent = ~0ull;      // 8B poison
constexpr unsigned kSentW = 0xFFFFFFFFu;         // 4B poison word (NaN)
constexpr int kHS = 3 * kB * kD;                 // shorts per h-split parity buf
constexpr int kRW = 2 * kB * kD;                 // floats per rw parity buf

__device__ inline unsigned short f2bf(float f) {  // RNE f32->bf16 bits
  unsigned u = __float_as_uint(f);
  u += 0x7FFFu + ((u >> 16) & 1u);
  return (unsigned short)(u >> 16);
}
__device__ inline float bf2f(unsigned short b) {
  return __uint_as_float(((unsigned)b) << 16);
}

__device__ inline float fast_tanh(float x) {       // (1-t)/(1+t), t=e^{-2|x|}
  const float ax = fabsf(x);
  const float t = __expf(-2.f * ax);
  const float r = (1.f - t) / (1.f + t);
  return copysignf(r, x);
}

// Fence-free cross-block transfer: relaxed agent-scope atomics compile to
// sc0|sc1 (L1+L2-bypass) accesses served by the device-coherent point.
__device__ inline void atst8(void* p, unsigned long long v) {
  __hip_atomic_store((unsigned long long*)p, v, __ATOMIC_RELAXED,
                     __HIP_MEMORY_SCOPE_AGENT);
}
__device__ inline unsigned long long atld8(const void* p) {
  return __hip_atomic_load((unsigned long long*)p, __ATOMIC_RELAXED,
                           __HIP_MEMORY_SCOPE_AGENT);
}
__device__ inline void atstf(float* p, float v) {
  __hip_atomic_store(p, v, __ATOMIC_RELAXED, __HIP_MEMORY_SCOPE_AGENT);
}
__device__ inline void atstu(unsigned* p, unsigned v) {
  __hip_atomic_store(p, v, __ATOMIC_RELAXED, __HIP_MEMORY_SCOPE_AGENT);
}
__device__ inline unsigned atldu(const unsigned* p) {
  return __hip_atomic_load((unsigned*)p, __ATOMIC_RELAXED,
                           __HIP_MEMORY_SCOPE_AGENT);
}

union U16 { unsigned long long ll[2]; unsigned wrd[4]; bf16x8 bv; float4 f4; };

// ---------------------------------------------------------------------------
// h-split store, consumer-lane-major layout (round-3/4 proven):
// element (part, w, j, half, l) at short-offset
//   part*16384 + ((w*8+j)<<9) + (half<<8) + l*4,  l = q*16 + batch.
__device__ inline void store_split(unsigned short* hs, int b, int d4, float4 h) {
  union { unsigned short u[4]; unsigned long long ll; } c2, c1, c0;
  float hv[4] = {h.x, h.y, h.z, h.w};
#pragma unroll
  for (int e = 0; e < 4; ++e) {
    unsigned short x = f2bf(hv[e]);
    float r = hv[e] - bf2f(x);
    unsigned short y = f2bf(r);
    float r2 = r - bf2f(y);
    unsigned short z = f2bf(r2);
    c2.u[e] = x; c1.u[e] = y; c0.u[e] = z;
  }
  const int w = d4 >> 8;
  const int j = (d4 >> 5) & 7;
  const int q = (d4 >> 3) & 3;
  const int hf = (d4 >> 2) & 1;
  const int off = ((w * 8 + j) << 9) + (hf << 8) + ((q * 16 + b) << 2);
  atst8(&hs[0 * 16384 + off], c2.ll);
  atst8(&hs[1 * 16384 + off], c1.ll);
  atst8(&hs[2 * 16384 + off], c0.ll);
}

// ---------------------------------------------------------------------------
// Round-14 = round-12 RESTORED VERBATIM (session best, 9280us). Round 13's
// pipelined polls regressed (+2%, FETCH +21MB): waits are producer-bound,
// detection was already sub-RT (the serial spin keeps its load in flight).
// Sixth failed sync-chain variant => the chain is at its measured floor:
// 2 irreducible IC hops/step + E[max] straggler jitter over the 64-block
// bipartite dependency. Weights-in-registers forces the 64-way column
// split (12MB weights vs 256KB/block) => the topology is forced.
//
// Fused kernel: blocks 0..63 = scan; blocks 64.. = xproj producers running
// in the scan's shadow (time-major tile order, atomic C-writes for IC
// visibility, data-as-flag xp handoff with late validation).
// Scan protocol (rounds 6/8/11/12 proven): data-as-flag hsplit + rw with
// NaN sentinels; advisory line-private tags (drain -> splits -> tag);
// certified repoison (hsplit post-barrier, rw pre-barrier); merged
// attention (one barrier/iter); tape in registers; fast transcendentals.
__global__ __launch_bounds__(256, 1)
void scan_kernel(const float* __restrict__ X, const float* __restrict__ Wx,
                 const float* __restrict__ Wh, const float* __restrict__ Ww,
                 const float* __restrict__ bh,
                 float* __restrict__ hall,              // [B,T,D] xp -> h
                 unsigned short* __restrict__ hsplit,   // [2][3][4][8][512] bf16
                 float* __restrict__ rw,                // [2][2][16][1024] f32
                 unsigned* __restrict__ hmark,          // [4][16] tags, 64B apart
                 float* __restrict__ out_tape,          // [B,N,D]
                 float* __restrict__ out_h) {           // [B,D]
  __shared__ float Xs[16][132];         // xproj staging (producer blocks)
  __shared__ float Ws[16][132];
  __shared__ f32x4 Cred[2][4][2][64];   // scan: cross-wave C partials (dbuf)
  __shared__ float red2[4][20];         // scan: [w][0..7]=wv [8..15]=h [16]=h.wv

  const int bid = blockIdx.x;
  const int tid = threadIdx.x;

  if (bid >= 64) {
    // ---- xproj producer: C[m,n] = sum_k X[m,k]*Wx[n,k] (round-1 proven
    //      body; time-major tile order; atomic C-writes for IC visibility)
    const int e = bid - 64;
    const int t_blk = e >> 7;           // 0..7  (time stratum, early first)
    const int b = (e >> 3) & 15;        // batch
    const int nb = e & 7;               // column block
    const int m0 = b * kT + t_blk * 128;
    const int n0 = nb * 128;
    const int tx = tid & 15;
    const int ty = tid >> 4;
    const int lr = tid >> 2;
    const int lc = (tid & 3) * 4;

    float acc[8][8];
#pragma unroll
    for (int i = 0; i < 8; ++i)
#pragma unroll
      for (int j = 0; j < 8; ++j) acc[i][j] = 0.f;

    for (int k0 = 0; k0 < kD; k0 += 16) {
      const float4 xa = *(const float4*)&X[(size_t)(m0 + lr) * kD + k0 + lc];
      const float4 xb = *(const float4*)&X[(size_t)(m0 + lr + 64) * kD + k0 + lc];
      const float4 wa = *(const float4*)&Wx[(size_t)(n0 + lr) * kD + k0 + lc];
      const float4 wb = *(const float4*)&Wx[(size_t)(n0 + lr + 64) * kD + k0 + lc];
      __syncthreads();
      Xs[lc + 0][lr] = xa.x; Xs[lc + 1][lr] = xa.y; Xs[lc + 2][lr] = xa.z; Xs[lc + 3][lr] = xa.w;
      Xs[lc + 0][lr + 64] = xb.x; Xs[lc + 1][lr + 64] = xb.y; Xs[lc + 2][lr + 64] = xb.z; Xs[lc + 3][lr + 64] = xb.w;
      Ws[lc + 0][lr] = wa.x; Ws[lc + 1][lr] = wa.y; Ws[lc + 2][lr] = wa.z; Ws[lc + 3][lr] = wa.w;
      Ws[lc + 0][lr + 64] = wb.x; Ws[lc + 1][lr + 64] = wb.y; Ws[lc + 2][lr + 64] = wb.z; Ws[lc + 3][lr + 64] = wb.w;
      __syncthreads();
#pragma unroll
      for (int k = 0; k < 16; ++k) {
        float a[8], bb[8];
        *(float4*)&a[0] = *(const float4*)&Xs[k][ty * 8];
        *(float4*)&a[4] = *(const float4*)&Xs[k][ty * 8 + 4];
        *(float4*)&bb[0] = *(const float4*)&Ws[k][tx * 8];
        *(float4*)&bb[4] = *(const float4*)&Ws[k][tx * 8 + 4];
#pragma unroll
        for (int i = 0; i < 8; ++i)
#pragma unroll
          for (int j = 0; j < 8; ++j) acc[i][j] += a[i] * bb[j];
      }
    }
#pragma unroll
    for (int i = 0; i < 8; ++i) {
      union { float f[8]; unsigned long long ll[4]; } row;
#pragma unroll
      for (int j = 0; j < 8; ++j) row.f[j] = acc[i][j];
      float* p = &hall[(size_t)(m0 + ty * 8 + i) * kD + n0 + tx * 8];
      atst8(p + 0, row.ll[0]);
      atst8(p + 2, row.ll[1]);
      atst8(p + 4, row.ll[2]);
      atst8(p + 6, row.ll[3]);
    }
    return;
  }

  // ===================== scan (round-11 body + xp polls) ====================
  const int g = bid;
  const int w = tid >> 6;    // wave 0..3 (split-K: k range [256w, 256w+256))
  const int ln = tid & 63;
  const int bat = ln & 15;   // A-row (batch) / B-col selector
  const bool tapeb = (g < kB);
  const int col0 = (g & 31) * 32;
  const int matw = g >> 5;

  // ---- weight prologue (plain loads; weights immutable) ----
  bf16x8 wf[3][2][8];
  {
    const float* Wsrc = matw ? Ww : Wh;
#pragma unroll
    for (int ct = 0; ct < 2; ++ct)
#pragma unroll
      for (int j = 0; j < 8; ++j) {
        const float* src = &Wsrc[(size_t)(col0 + ct * 16 + bat) * kD + (w * 8 + j) * 32 + ((ln >> 4)) * 8];
        float v[8];
        *(float4*)&v[0] = *(const float4*)src;
        *(float4*)&v[4] = *(const float4*)(src + 4);
        union { unsigned short u[8]; bf16x8 b; } e2, e1, e0;
#pragma unroll
        for (int e = 0; e < 8; ++e) {
          unsigned short a = f2bf(v[e]);
          float r = v[e] - bf2f(a);
          unsigned short b2 = f2bf(r);
          float r2 = r - bf2f(b2);
          unsigned short c = f2bf(r2);
          e2.u[e] = a; e1.u[e] = b2; e0.u[e] = c;
        }
        wf[0][ct][j] = e2.b;
        wf[1][ct][j] = e1.b;
        wf[2][ct][j] = e0.b;
      }
  }

  // ---- tape-block bootstrap: tape=0 (registers), h(1)=tanh(xp0) ----
  float4 hprev = make_float4(0.f, 0.f, 0.f, 0.f);
  float4 bh4 = make_float4(0.f, 0.f, 0.f, 0.f);
  float4 tpr[kN];                       // the tape slice: thread-private
#pragma unroll
  for (int n = 0; n < kN; ++n) tpr[n] = make_float4(0.f, 0.f, 0.f, 0.f);
  const int d4 = tid * 4;
  if (tapeb) {
    float* px0 = &hall[(size_t)g * kT * kD + d4];
    U16 ux;
    for (;;) {                         // poll xp0 (xproj data-as-flag)
      ux.ll[0] = atld8(px0); ux.ll[1] = atld8(px0 + 2);
      int bad = 0;
#pragma unroll
      for (int k2 = 0; k2 < 4; ++k2) bad |= (ux.wrd[k2] == kSentW);
      if (!bad) break;
      __builtin_amdgcn_s_sleep(1);
    }
    asm volatile("" ::: "memory");
    hprev.x = tanhf(ux.f4.x); hprev.y = tanhf(ux.f4.y);
    hprev.z = tanhf(ux.f4.z); hprev.w = tanhf(ux.f4.w);
    *(float4*)px0 = hprev;             // plain: host-read-only afterward
    store_split(hsplit, g, d4, hprev);           // parity 0 = h(1)
    asm volatile("s_waitcnt vmcnt(0)" ::: "memory");  // one-time drain
    if (ln == 0) atstu(&hmark[(w * 16 + g) * 16], 1u);  // advisory tag
    bh4 = *(const float4*)&bh[d4];
  }

  for (int t = 0; t < kT; ++t) {
    const int p = t & 1;
    const unsigned short* hb = hsplit + p * kHS;

    // speculative xp load (validated LATE, before the tanh): latency hides
    // under the whole step; producer is far ahead after the first steps
    U16 uxp;
    float* px = nullptr;
    if (tapeb && t < kT - 1) {
      px = &hall[((size_t)g * kT + (t + 1)) * kD + d4];
      uxp.ll[0] = atld8(px); uxp.ll[1] = atld8(px + 2);
    }

    // ---- phase 1: advisory tag spin (cheap throttle; correctness comes
    //      from the sentinel-validated fragment loads below) ----
    {
      const unsigned need = (unsigned)(t + 1);
      const unsigned* mk = &hmark[(w * 16 + bat) * 16];
      for (;;) {
        unsigned v = 0;
        if ((ln >> 4) == 0) v = atldu(mk);
        v = __shfl(v, bat);              // broadcast from the q==0 lane
        if (v >= need) break;
        __builtin_amdgcn_s_sleep(1);
      }
      asm volatile("" ::: "memory");
    }
    // A fragments: dense lane-major loads, sentinel-validated (an 8B chunk
    // of 0xFFFF shorts is unreachable by finite bf16 split parts).
    U16 uf[3][8];
    const unsigned short* hw0 = hb + (w << 12) + (ln << 2);  // w*4096 + ln*4
    for (;;) {
      int bad = 0;
#pragma unroll
      for (int j = 0; j < 8; ++j) {
        const unsigned short* p0 = hw0 + (j << 9);
#pragma unroll
        for (int part = 0; part < 3; ++part) {
          uf[part][j].ll[0] = atld8(p0 + part * 16384);
          uf[part][j].ll[1] = atld8(p0 + part * 16384 + 256);
        }
      }
#pragma unroll
      for (int j = 0; j < 8; ++j)
#pragma unroll
        for (int part = 0; part < 3; ++part)
          bad |= (uf[part][j].ll[0] == kSent) | (uf[part][j].ll[1] == kSent);
      if (!bad) break;
      __builtin_amdgcn_s_sleep(1);
    }
    asm volatile("" ::: "memory");

    // ---- 6-product triple-split MFMA ----
    f32x4 zf = {0.f, 0.f, 0.f, 0.f};
    f32x4 acc[2][2] = {{zf, zf}, {zf, zf}};
#pragma unroll
    for (int j = 0; j < 8; ++j) {
      const int s = j & 1;
#pragma unroll
      for (int ct = 0; ct < 2; ++ct) {
        f32x4 a = acc[ct][s];
        a = __builtin_amdgcn_mfma_f32_16x16x32_bf16(uf[0][j].bv, wf[0][ct][j], a, 0, 0, 0);
        a = __builtin_amdgcn_mfma_f32_16x16x32_bf16(uf[0][j].bv, wf[1][ct][j], a, 0, 0, 0);
        a = __builtin_amdgcn_mfma_f32_16x16x32_bf16(uf[1][j].bv, wf[0][ct][j], a, 0, 0, 0);
        a = __builtin_amdgcn_mfma_f32_16x16x32_bf16(uf[0][j].bv, wf[2][ct][j], a, 0, 0, 0);
        a = __builtin_amdgcn_mfma_f32_16x16x32_bf16(uf[2][j].bv, wf[0][ct][j], a, 0, 0, 0);
        a = __builtin_amdgcn_mfma_f32_16x16x32_bf16(uf[1][j].bv, wf[1][ct][j], a, 0, 0, 0);
        acc[ct][s] = a;
      }
    }
    Cred[p][w][0][ln] = acc[0][0] + acc[0][1];
    Cred[p][w][1][ln] = acc[1][0] + acc[1][1];
    __syncthreads();
    if (tid < 128) {
      const int ct = tid >> 6, l2 = tid & 63;
      f32x4 sv = Cred[p][0][ct][l2] + Cred[p][1][ct][l2] +
                 Cred[p][2][ct][l2] + Cred[p][3][ct][l2];
      float* dst = rw + p * kRW + matw * (kB * kD);
      const int col = col0 + ct * 16 + (l2 & 15);
      const int m0 = (l2 >> 4) * 4;  // C/D: col=lane&15, row=(lane>>4)*4+reg (m89)
#pragma unroll
      for (int r = 0; r < 4; ++r) atstf(&dst[(size_t)(m0 + r) * kD + col], sv[r]);
      // no drain, no flag: consumers validate the data itself
    }
    // no second barrier: next iteration writes Cred[p^1]

    if (!tapeb) continue;

    // ---- P2 (tape blocks), merged-attention flow (tape in registers) ----
    const int b = g;
    float* rwp = rw + p * kRW;
    float* pr = &rwp[b * kD + d4];
    float* pw = &rwp[kB * kD + b * kD + d4];

    // (1) h-dot tree on the OLD tape -- useful work while rw propagates
    {
      float ph[kN];
#pragma unroll
      for (int n = 0; n < kN; ++n)
        ph[n] = hprev.x * tpr[n].x + hprev.y * tpr[n].y +
                hprev.z * tpr[n].z + hprev.w * tpr[n].w;
#pragma unroll
      for (int off = 32; off > 0; off >>= 1)
#pragma unroll
        for (int n = 0; n < kN; ++n) ph[n] += __shfl_xor(ph[n], off);
      if (ln == 0)
#pragma unroll
        for (int n = 0; n < kN; ++n) red2[w][8 + n] = ph[n];
    }

    // (2) poll wv AND rh (both must be valid pre-barrier: the repoison
    //     certification needs each thread's rh/wv chunks to certify blocks
    //     (0,cb) and (1,cb); the barrier pools all 64)
    float4 rh4, wv4;
    for (;;) {
      U16 ur, uw;
      ur.ll[0] = atld8(pr); ur.ll[1] = atld8(pr + 2);
      uw.ll[0] = atld8(pw); uw.ll[1] = atld8(pw + 2);
      int bad = 0;
#pragma unroll
      for (int k2 = 0; k2 < 4; ++k2)
        bad |= (ur.wrd[k2] == kSentW) | (uw.wrd[k2] == kSentW);
      if (!bad) { rh4 = ur.f4; wv4 = uw.f4; break; }
      __builtin_amdgcn_s_sleep(1);
    }
    asm volatile("" ::: "memory");       // no reorder across the data-poll
    // (3) re-poison this rw parity for its t+2 reuse (drained by the
    //     barrier's implicit vmcnt(0) below)
    atst8(pr, kSent); atst8(pr + 2, kSent);
    atst8(pw, kSent); atst8(pw + 2, kSent);

    // (4) wv-dot tree: wv.tp_old[n] (8) + h.wv (1)
    {
      float pv[9];
#pragma unroll
      for (int n = 0; n < kN; ++n)
        pv[n] = wv4.x * tpr[n].x + wv4.y * tpr[n].y +
                wv4.z * tpr[n].z + wv4.w * tpr[n].w;
      pv[8] = hprev.x * wv4.x + hprev.y * wv4.y + hprev.z * wv4.z + hprev.w * wv4.w;
#pragma unroll
      for (int off = 32; off > 0; off >>= 1)
#pragma unroll
        for (int n = 0; n < 9; ++n) pv[n] += __shfl_xor(pv[n], off);
      if (ln == 0) {
#pragma unroll
        for (int n = 0; n < kN; ++n) red2[w][n] = pv[n];
        red2[w][16] = pv[8];
      }
    }
    __syncthreads();   // the ONLY attn barrier (pools rw validation + red2)

    // (5) repoison hsplit parity p (own 3 chunks; certified consumed by the
    //     barrier; drained by the publish vmcnt(0) below)
    {
      unsigned short* hp0 = hsplit + p * kHS;
      const int off = (((d4 >> 8) * 8 + ((d4 >> 5) & 7)) << 9) +
                      (((d4 >> 2) & 1) << 8) + ((((d4 >> 3) & 3) * 16 + b) << 2);
      atst8(&hp0[0 * 16384 + off], kSent);
      atst8(&hp0[1 * 16384 + off], kSent);
      atst8(&hp0[2 * 16384 + off], kSent);
    }

    // (6) cross-wave sums + write-attention softmax
    float s_h[kN], s_hwv;
    float wa[kN];
    {
      float mx = -1e30f;
#pragma unroll
      for (int n = 0; n < kN; ++n) {
        const float sc = kScale * (red2[0][n] + red2[1][n] + red2[2][n] + red2[3][n]);
        wa[n] = sc;
        mx = fmaxf(mx, sc);
        s_h[n] = red2[0][8 + n] + red2[1][8 + n] + red2[2][8 + n] + red2[3][8 + n];
      }
      s_hwv = red2[0][16] + red2[1][16] + red2[2][16] + red2[3][16];
      float ssum = 0.f;
#pragma unroll
      for (int n = 0; n < kN; ++n) { wa[n] = __expf(wa[n] - mx); ssum += wa[n]; }
      const float inv = 1.f / ssum;
#pragma unroll
      for (int n = 0; n < kN; ++n) wa[n] *= inv;
    }

    // (7) tape update, in registers (thread-private slice)
#pragma unroll
    for (int n = 0; n < kN; ++n) {
      const float wn = wa[n], om = 1.f - wn;
      tpr[n].x = tpr[n].x * om + wv4.x * wn;
      tpr[n].y = tpr[n].y * om + wv4.y * wn;
      tpr[n].z = tpr[n].z * om + wv4.z * wn;
      tpr[n].w = tpr[n].w * om + wv4.w * wn;
    }

    if (t == kT - 1) {
#pragma unroll
      for (int n = 0; n < kN; ++n)
        *(float4*)&out_tape[((size_t)b * kN + n) * kD + d4] = tpr[n];
      *(float4*)&out_h[b * kD + d4] = hprev;
      continue;
    }

    // (8) read-attention via the distributive identity:
    //     h.tp_new[n] = (1-wa[n])*s_h[n] + wa[n]*s_hwv
    float ra[kN];
    {
      float mx = -1e30f;
#pragma unroll
      for (int n = 0; n < kN; ++n) {
        const float sc = kScale * (s_h[n] * (1.f - wa[n]) + s_hwv * wa[n]);
        ra[n] = sc;
        mx = fmaxf(mx, sc);
      }
      float ssum = 0.f;
#pragma unroll
      for (int n = 0; n < kN; ++n) { ra[n] = __expf(ra[n] - mx); ssum += ra[n]; }
      const float inv = 1.f / ssum;
#pragma unroll
      for (int n = 0; n < kN; ++n) ra[n] *= inv;
    }

    // (9) rv from the UPDATED register tape
    float4 rv = make_float4(0.f, 0.f, 0.f, 0.f);
#pragma unroll
    for (int n = 0; n < kN; ++n) {
      rv.x += ra[n] * tpr[n].x; rv.y += ra[n] * tpr[n].y;
      rv.z += ra[n] * tpr[n].z; rv.w += ra[n] * tpr[n].w;
    }

    // (9b) LATE xp validation (speculative load issued at step top; xproj
    //      writes each location once, atomically per 8B chunk)
    for (;;) {
      int bad = 0;
#pragma unroll
      for (int k2 = 0; k2 < 4; ++k2) bad |= (uxp.wrd[k2] == kSentW);
      if (!bad) break;
      __builtin_amdgcn_s_sleep(1);
      uxp.ll[0] = atld8(px); uxp.ll[1] = atld8(px + 2);
    }
    asm volatile("" ::: "memory");
    const float4 xp4 = uxp.f4;

    float4 hn;
    hn.x = fast_tanh(xp4.x + rh4.x + rv.x + bh4.x);
    hn.y = fast_tanh(xp4.y + rh4.y + rv.y + bh4.y);
    hn.z = fast_tanh(xp4.z + rh4.z + rv.z + bh4.z);
    hn.w = fast_tanh(xp4.w + rh4.w + rv.w + bh4.w);

    // (10) publish, round-8 proven order: (near-free) drain enforcing
    //      repoison->splits visibility order, splits, THEN tag, hall last.
    asm volatile("s_waitcnt vmcnt(0)" ::: "memory");
    store_split(hsplit + (p ^ 1) * kHS, b, d4, hn);   // publish h(t+2)
    if (ln == 0) atstu(&hmark[(w * 16 + b) * 16], (unsigned)(t + 2));  // advisory
    *(float4*)&hall[((size_t)b * kT + (t + 1)) * kD + d4] = hn;  // off-path
    hprev = hn;
  }
}

}  // namespace

extern "C" void kernel_launch(void* const* d_in, const int* in_sizes, int n_in,
                              void* d_out, int out_size, void* d_ws, size_t ws_size,
                              hipStream_t stream) {
  const float* x  = (const float*)d_in[0];
  const float* Wh = (const float*)d_in[1];
  const float* Wx = (const float*)d_in[2];
  const float* bh = (const float*)d_in[3];
  const float* Ww = (const float*)d_in[4];

  float* out = (float*)d_out;
  float* hall = out;                                  // [B,T,D]
  float* out_tape = out + (size_t)kB * kT * kD;       // [B,N,D]
  float* out_h = out_tape + (size_t)kB * kN * kD;     // [B,D]

  // ws: [0,4096) hmark tags (64 x 64B lines); [4096,+192K) hsplit[2];
  //     then rw[2] (256K). hsplit, rw AND hall are NaN-poisoned each launch
  //     (stream-ordered before the fused kernel: data-as-flag bootstrap).
  unsigned* hmark = (unsigned*)d_ws;
  unsigned short* hsplit = (unsigned short*)((char*)d_ws + 4096);
  float* rw = (float*)((char*)d_ws + 4096 + 2 * kHS * (int)sizeof(unsigned short));

  hipMemsetAsync(d_ws, 0, 4096, stream);             // tags = 0
  hipMemsetAsync((char*)d_ws + 4096, 0xFF,
                 2 * kHS * sizeof(unsigned short) + 2 * kRW * sizeof(float),
                 stream);                            // poison hsplit + rw
  hipMemsetAsync(hall, 0xFF, (size_t)kB * kT * kD * sizeof(float),
                 stream);                            // poison hall (xp flags)

  scan_kernel<<<64 + 1024, 256, 0, stream>>>(x, Wx, Wh, Ww, bh, hall, hsplit,
                                             rw, hmark, out_tape, out_h);
}